// Round 7
// baseline (766.859 us; speedup 1.0000x reference)
//
#include <hip/hip_runtime.h>
#include <math.h>

#define NB 32
#define NN 4096
#define DK 256
#define DV 256

// ---- K1: H prep. Column norms (axis=1): XLA/np outer-axis reduce =
// strictly sequential over d, separate mul/add rounding.
// Hn = H / max(nrm,1e-8) (CR div). HT = raw transpose.
__global__ __launch_bounds__(256) void k_hprep(const float* __restrict__ H,
    float* __restrict__ Hn, float* __restrict__ HT) {
  const int b = blockIdx.x;
  const int t = threadIdx.x;
  const float* __restrict__ Hb = H + (size_t)b * DK * DV;

  float ss = 0.0f;
  for (int d = 0; d < DK; ++d) {
    float h = Hb[d * DV + t];
    ss = __fadd_rn(ss, __fmul_rn(h, h));
  }
  __shared__ float nr[DV];
  nr[t] = fmaxf(__fsqrt_rn(ss), 1e-8f);
  __syncthreads();

  for (int d = 0; d < DK; ++d) {
    float h = Hb[d * DV + t];
    Hn[(size_t)b * DK * DV + d * DV + t] = __fdiv_rn(h, nr[t]);
  }

  __shared__ float tile[32][33];
  const int c = t & 31, g = t >> 5;
  for (int k0 = 0; k0 < DV; k0 += 32) {
    for (int d0 = 0; d0 < DK; d0 += 32) {
      __syncthreads();
#pragma unroll
      for (int j = 0; j < 4; ++j) {
        int dl = g + 8 * j;
        tile[dl][c] = Hb[(size_t)(d0 + dl) * DV + k0 + c];
      }
      __syncthreads();
#pragma unroll
      for (int j = 0; j < 4; ++j) {
        int kl = g + 8 * j;
        HT[(size_t)b * DV * DK + (size_t)(k0 + kl) * DK + d0 + c] = tile[c][kl];
      }
    }
  }
}

// ---- K2: 16 rows/block. XLA-CPU-replica: sequential C-norm, seq-FMA sims,
// CR exp with max-sub, STRICTLY SEQUENTIAL Z, alpha-bit top-16 ties-LOW. ----
__global__ __launch_bounds__(256) void k_main(
    const float* __restrict__ C, const float* __restrict__ Hn,
    const float* __restrict__ HT, const float* __restrict__ temp,
    float* __restrict__ out) {
  const int b = blockIdx.x >> 8;
  const int n0 = (blockIdx.x & 255) * 16;
  const int t = threadIdx.x;
  const int w = t >> 6, l = t & 63;

  __shared__ float cs[16][DK];
  __shared__ float xs[16][DV];
  __shared__ float es[4][DV];
  __shared__ float nrm16[16];

  const float* __restrict__ Cb = C + ((size_t)b * NN + n0) * DK;
  for (int i = t; i < 16 * DK; i += 256) ((float*)cs)[i] = Cb[i];
  __syncthreads();

  // ---- C row norms: STRICT SEQUENTIAL chain over 256 (XLA-CPU reduce) ----
  if (t < 16) {
    float ss = 0.0f;
    for (int d = 0; d < DK; ++d) {
      float c = cs[t][d];
      ss = __fadd_rn(ss, __fmul_rn(c, c));
    }
    nrm16[t] = fmaxf(__fsqrt_rn(ss), 1e-8f);
  }
  __syncthreads();
  for (int i = t; i < 16 * DK; i += 256) {
    const int r = i >> 8, d = i & 255;
    cs[r][d] = __fdiv_rn(cs[r][d], nrm16[r]);
  }
  __syncthreads();

  // ---- sims: sequential-d single FMA chain (Eigen/oneDNN gebp order) ----
  float acc[16];
#pragma unroll
  for (int n = 0; n < 16; ++n) acc[n] = 0.0f;
  const float* __restrict__ Hnb = Hn + (size_t)b * DK * DV;
  for (int d0 = 0; d0 < DK; d0 += 4) {
    const float h0 = Hnb[(size_t)(d0 + 0) * DV + t];
    const float h1 = Hnb[(size_t)(d0 + 1) * DV + t];
    const float h2 = Hnb[(size_t)(d0 + 2) * DV + t];
    const float h3 = Hnb[(size_t)(d0 + 3) * DV + t];
#pragma unroll
    for (int n = 0; n < 16; ++n) {
      acc[n] = fmaf(cs[n][d0 + 0], h0, acc[n]);
      acc[n] = fmaf(cs[n][d0 + 1], h1, acc[n]);
      acc[n] = fmaf(cs[n][d0 + 2], h2, acc[n]);
      acc[n] = fmaf(cs[n][d0 + 3], h3, acc[n]);
    }
  }
#pragma unroll
  for (int n = 0; n < 16; ++n) xs[n][t] = acc[n];
  __syncthreads();

  const float tt = fmaxf(temp[0], 0.1f);
  const float tp = __fadd_rn(tt, 1e-8f);   // f32: 1.0+1e-8 -> 1.0 exactly

  for (int rr = 0; rr < 4; ++rr) {
    const int r = w * 4 + rr;
    const int grow = b * NN + n0 + r;
    const float x0 = __fdiv_rn(xs[r][l], tp);
    const float x1 = __fdiv_rn(xs[r][l + 64], tp);
    const float x2 = __fdiv_rn(xs[r][l + 128], tp);
    const float x3 = __fdiv_rn(xs[r][l + 192], tp);
    float m = fmaxf(fmaxf(x0, x1), fmaxf(x2, x3));
#pragma unroll
    for (int s = 1; s < 64; s <<= 1) m = fmaxf(m, __shfl_xor(m, s, 64));
    // correctly-rounded f32 exp (glibc expf replica via double)
    const float e0 = (float)exp((double)__fsub_rn(x0, m));
    const float e1 = (float)exp((double)__fsub_rn(x1, m));
    const float e2 = (float)exp((double)__fsub_rn(x2, m));
    const float e3 = (float)exp((double)__fsub_rn(x3, m));
    es[w][l] = e0; es[w][l + 64] = e1; es[w][l + 128] = e2; es[w][l + 192] = e3;
    __syncthreads();  // uniform: all waves iterate rr=0..3

    // ---- Z: STRICT SEQUENTIAL chain over 256 in index order ----
    float zacc = 0.0f;
    if (l == 0) {
      for (int k = 0; k < DV; ++k) zacc = __fadd_rn(zacc, es[w][k]);
    }
    const float Z = __shfl(zacc, 0, 64);

    // alpha = fl32(e / Z); selection on alpha bits, ties -> LOWER index
    const float a0 = __fdiv_rn(e0, Z);
    const float a1 = __fdiv_rn(e1, Z);
    const float a2 = __fdiv_rn(e2, Z);
    const float a3 = __fdiv_rn(e3, Z);
    unsigned long long k0 = ((unsigned long long)__float_as_uint(a0) << 8) | (unsigned long long)(255 - l);
    unsigned long long k1 = ((unsigned long long)__float_as_uint(a1) << 8) | (unsigned long long)(255 - (l + 64));
    unsigned long long k2 = ((unsigned long long)__float_as_uint(a2) << 8) | (unsigned long long)(255 - (l + 128));
    unsigned long long k3 = ((unsigned long long)__float_as_uint(a3) << 8) | (unsigned long long)(255 - (l + 192));

    float aval[16];
    int idx[16];
#pragma unroll
    for (int e = 0; e < 16; ++e) {
      unsigned long long loc = k0 > k1 ? k0 : k1;
      loc = loc > k2 ? loc : k2;
      loc = loc > k3 ? loc : k3;
#pragma unroll
      for (int s = 1; s < 64; s <<= 1) {
        unsigned long long o = __shfl_xor(loc, s, 64);
        loc = o > loc ? o : loc;
      }
      const int wk = 255 - (int)(loc & 0xFFull);
      aval[e] = __uint_as_float((unsigned int)(loc >> 8));
      idx[e] = wk;
      const bool mine = (wk & 63) == l;
      const int slot = wk >> 6;
      k0 = (mine && slot == 0) ? 0ull : k0;
      k1 = (mine && slot == 1) ? 0ull : k1;
      k2 = (mine && slot == 2) ? 0ull : k2;
      k3 = (mine && slot == 3) ? 0ull : k3;
    }

    // renormalize selected; 2% bf16-rounded tolerance -> fp32 fine
    float S = aval[0];
#pragma unroll
    for (int e = 1; e < 16; ++e) S = __fadd_rn(S, aval[e]);
    const float S1 = __fadd_rn(S, 1e-8f);

    float o0 = 0.f, o1 = 0.f, o2 = 0.f, o3 = 0.f;
#pragma unroll
    for (int e = 0; e < 16; ++e) {
      const float wj = __fdiv_rn(aval[e], S1);
      const float* __restrict__ hr = HT + ((size_t)b * DV + idx[e]) * DK;
      o0 = fmaf(wj, hr[l], o0);
      o1 = fmaf(wj, hr[l + 64], o1);
      o2 = fmaf(wj, hr[l + 128], o2);
      o3 = fmaf(wj, hr[l + 192], o3);
    }
    float* __restrict__ orow = out + (size_t)grow * DK;
    orow[l] = o0;
    orow[l + 64] = o1;
    orow[l + 128] = o2;
    orow[l + 192] = o3;
    __syncthreads();  // protect es before next rr overwrite (uniform)
  }
}

extern "C" void kernel_launch(void* const* d_in, const int* in_sizes, int n_in,
                              void* d_out, int out_size, void* d_ws, size_t ws_size,
                              hipStream_t stream) {
  const float* C = (const float*)d_in[0];
  const float* H = (const float*)d_in[1];
  const float* temp = (const float*)d_in[2];
  float* out = (float*)d_out;
  char* ws = (char*)d_ws;

  float* Hn = (float*)ws;                 // 8 MiB
  float* HT = (float*)(ws + 8388608);     // 8 MiB

  hipLaunchKernelGGL(k_hprep, dim3(NB), dim3(256), 0, stream, H, Hn, HT);
  hipLaunchKernelGGL(k_main, dim3(NB * (NN / 16)), dim3(256), 0, stream,
                     C, Hn, HT, temp, out);
}